// Round 4
// baseline (123.962 us; speedup 1.0000x reference)
//
#include <hip/hip_runtime.h>
#include <hip/hip_bf16.h>
#include <math.h>

typedef short bf16x8 __attribute__((ext_vector_type(8)));
typedef short bf16x4 __attribute__((ext_vector_type(4)));
typedef float f32x4 __attribute__((ext_vector_type(4)));

#define STATE 24
#define L1N 100

// ---- padded bf16 weight image (u16 units), built once per launch in d_ws ----
#define W1_STRIDE 40              // K 24 -> pad 40 halves (80 B)
#define K_STRIDE 136              // K 100 -> pad 136 halves (272 B)
#define W1_OFF 0                  // 100 rows x 40
#define W2_OFF 4000               // 100 rows x 136
#define WH_OFF 17600              // 27 rows x 136 (6 mean + 21 chol)
#define IMG_U32 10752             // 43008 B
#define IMG_BYTES (IMG_U32 * 4)
#define IMG_HALVES (IMG_U32 * 2)

#define X_HALVES (32 * K_STRIDE)  // per-wave X: 32 rows x 136 = 4352 halves
#define NWAVES 4
#define LDS_BYTES (IMG_BYTES + NWAVES * X_HALVES * 2)   // 77824 B -> 2 blocks/CU

#define GRID 512                  // 2 persistent-ish blocks per CU

__device__ __constant__ int CHOFF[21] = {0,6,7,12,13,14,18,19,20,21,24,25,26,27,28,30,31,32,33,34,35};
__device__ __constant__ int ZOFF[15]  = {1,2,3,4,5,8,9,10,11,15,16,17,22,23,29};

__device__ inline unsigned short f2bf(float f) {
    union { float f; unsigned u; } v; v.f = f;
    unsigned r = v.u + 0x7FFFu + ((v.u >> 16) & 1u);   // RNE
    return (unsigned short)(r >> 16);
}
__device__ inline unsigned pkbf(float lo, float hi) {
    __hip_bfloat162 h = __float22bfloat162_rn(float2{lo, hi});
    return *(const unsigned*)&h;
}
__device__ inline float fast_tanh(float x) {
    float e = __builtin_amdgcn_exp2f(x * 2.8853900817779268f);   // e^{2x}
    return 1.0f - 2.0f * __builtin_amdgcn_rcpf(e + 1.0f);
}
__device__ inline float fast_softplus(float v) {
    float u = __builtin_amdgcn_exp2f(fabsf(v) * -1.4426950408889634f);
    float l = __builtin_amdgcn_logf(1.0f + u) * 0.6931471805599453f;
    return fmaxf(v, 0.0f) + l;
}

// ---- prologue: build padded bf16 weight image in workspace ----
__global__ __launch_bounds__(256) void prep_weights(
    const float* __restrict__ W1, const float* __restrict__ W2,
    const float* __restrict__ Wm, const float* __restrict__ Wc,
    unsigned* __restrict__ img)
{
    int i = blockIdx.x * 256 + threadIdx.x;
    if (i >= IMG_U32) return;
    float lo = 0.f, hi = 0.f;
    if (i < 2000) {                            // W1: 100 rows x 20 u32
        int r = i / 20, k = (i % 20) * 2;
        if (k < STATE)     lo = W1[r * STATE + k];
        if (k + 1 < STATE) hi = W1[r * STATE + k + 1];
    } else if (i < 8800) {                     // W2: 100 rows x 68 u32
        int j = i - 2000, r = j / 68, k = (j % 68) * 2;
        if (k < L1N)     lo = W2[r * L1N + k];
        if (k + 1 < L1N) hi = W2[r * L1N + k + 1];
    } else if (i < 10636) {                    // [Wm;Wc]: 27 rows x 68 u32
        int j = i - 8800, r = j / 68, k = (j % 68) * 2;
        const float* src = (r < 6) ? (Wm + r * L1N) : (Wc + (r - 6) * L1N);
        if (k < L1N)     lo = src[k];
        if (k + 1 < L1N) hi = src[k + 1];
    }
    img[i] = pkbf(lo, hi);
}

// Operand order: A = weight frag (M = features), B = activation frag (N = rows).
// D lane mapping (verified r2/r3 relabeled): n=col=lane&15 = batch row,
// m=row=q*4+i = feature -> lane holds 4 CONTIGUOUS features of one row
// -> ds_write_b64 write-back instead of 4x ds_write_b16.
__global__ __launch_bounds__(256, 2) void actor_mfma(
    const float* __restrict__ states,
    const unsigned* __restrict__ img,
    const float* __restrict__ b1, const float* __restrict__ b2,
    const float* __restrict__ bm, const float* __restrict__ bc,
    float* __restrict__ out_mean, float* __restrict__ out_chol, int ntiles)
{
    extern __shared__ __align__(16) unsigned short smem[];
    const int tid = threadIdx.x;
    {   // stage prebuilt bf16 image once per (persistent) block
        const uint4* src = (const uint4*)img;
        uint4* dst = (uint4*)smem;
        for (int i = tid; i < IMG_BYTES / 16; i += 256) dst[i] = src[i];
    }
    const int wave = tid >> 6, lane = tid & 63, q = lane >> 4, c = lane & 15;
    unsigned short* W1s = smem + W1_OFF;
    unsigned short* W2s = smem + W2_OFF;
    unsigned short* Whs = smem + WH_OFF;
    unsigned short* X   = smem + IMG_HALVES + wave * X_HALVES;
    {   // zero K-pad cols 96..135 of own-wave X (stays zero across iters)
        unsigned* xz = (unsigned*)X;
        #pragma unroll
        for (int it = 0; it < 10; ++it) {
            int i = it * 64 + lane;            // 0..639
            int r = i / 20, s = i - r * 20;
            xz[r * 68 + 48 + s] = 0u;
        }
    }
    __syncthreads();

    // ---- per-lane loop invariants: biases + epilogue routing ----
    f32x4 bias1[7], bias2[7];
    #pragma unroll
    for (int nt = 0; nt < 7; ++nt)
        #pragma unroll
        for (int i = 0; i < 4; ++i) {
            int f = nt * 16 + q * 4 + i; f = f < L1N ? f : L1N - 1;
            bias1[nt][i] = b1[f]; bias2[nt][i] = b2[f];
        }
    f32x4 bias3[2]; int eoff[8], ekind[8];
    #pragma unroll
    for (int ht = 0; ht < 2; ++ht)
        #pragma unroll
        for (int i = 0; i < 4; ++i) {
            int f = ht * 16 + q * 4 + i, e = ht * 4 + i;
            if (f < 6)       { bias3[ht][i] = bm[f];     eoff[e] = f;            ekind[e] = 0; }
            else if (f < 27) { bias3[ht][i] = bc[f - 6]; eoff[e] = CHOFF[f - 6]; ekind[e] = 1; }
            else             { bias3[ht][i] = 0.f;       eoff[e] = 0;            ekind[e] = -1; }
        }
    int zoff_[8], zrow_[8];
    #pragma unroll
    for (int it = 0; it < 8; ++it) {
        int idx = it * 64 + lane;              // 0..480+
        int r = idx / 15;
        zrow_[it] = r; zoff_[it] = ZOFF[idx - r * 15 < 15 ? idx - r * 15 : 0];
    }

    float4 sv[4];
    auto loadStates = [&](int tt) {
        if (tt < ntiles && q < 3) {
            long rb = (long)tt * 128 + wave * 32;
            #pragma unroll
            for (int u = 0; u < 2; ++u) {
                const float* p = states + (rb + u * 16 + c) * STATE + q * 8;
                sv[u * 2]     = *(const float4*)p;
                sv[u * 2 + 1] = *(const float4*)(p + 4);
            }
        }
    };
    loadStates(blockIdx.x);

    for (int t = blockIdx.x; t < ntiles; t += GRID) {
        const long rowW = (long)t * 128 + wave * 32;

        // convert current states, then prefetch next tile
        union { bf16x8 v; unsigned u[4]; } sb[2];
        #pragma unroll
        for (int u = 0; u < 2; ++u) {
            if (q < 3) {
                sb[u].u[0] = pkbf(sv[u*2].x,   sv[u*2].y);
                sb[u].u[1] = pkbf(sv[u*2].z,   sv[u*2].w);
                sb[u].u[2] = pkbf(sv[u*2+1].x, sv[u*2+1].y);
                sb[u].u[3] = pkbf(sv[u*2+1].z, sv[u*2+1].w);
            } else sb[u].u[0] = sb[u].u[1] = sb[u].u[2] = sb[u].u[3] = 0u;
        }
        loadStates(t + GRID);

        // ---- GEMM1: x1 = relu(W1 @ s^T + b1) ----
        #pragma unroll
        for (int nt = 0; nt < 7; ++nt) {
            int wr = nt * 16 + c; wr = wr < L1N ? wr : L1N - 1;
            bf16x8 wf = *(const bf16x8*)&W1s[wr * W1_STRIDE + q * 8];
            #pragma unroll
            for (int u = 0; u < 2; ++u) {
                f32x4 acc = bias1[nt];
                acc = __builtin_amdgcn_mfma_f32_16x16x32_bf16(wf, sb[u].v, acc, 0, 0, 0);
                if (nt * 16 + q * 4 < L1N) {   // features nt*16+q*4..+3 all valid
                    bf16x4 pk;
                    #pragma unroll
                    for (int i = 0; i < 4; ++i) pk[i] = (short)f2bf(fmaxf(acc[i], 0.f));
                    *(bf16x4*)&X[(u * 16 + c) * K_STRIDE + nt * 16 + q * 4] = pk;
                }
            }
        }

        // ---- GEMM2: x2 = relu(W2 @ x1^T + b2), K=128 padded ----
        bf16x8 ab[2][4];
        #pragma unroll
        for (int u = 0; u < 2; ++u)
            #pragma unroll
            for (int ks = 0; ks < 4; ++ks)
                ab[u][ks] = *(const bf16x8*)&X[(u * 16 + c) * K_STRIDE + ks * 32 + q * 8];
        f32x4 acc2[2][7];
        #pragma unroll
        for (int u = 0; u < 2; ++u)
            #pragma unroll
            for (int nt = 0; nt < 7; ++nt) acc2[u][nt] = bias2[nt];
        #pragma unroll
        for (int ks = 0; ks < 4; ++ks)
            #pragma unroll
            for (int nt = 0; nt < 7; ++nt) {
                int wr = nt * 16 + c; wr = wr < L1N ? wr : L1N - 1;
                bf16x8 wf = *(const bf16x8*)&W2s[wr * K_STRIDE + ks * 32 + q * 8];
                acc2[0][nt] = __builtin_amdgcn_mfma_f32_16x16x32_bf16(wf, ab[0][ks], acc2[0][nt], 0, 0, 0);
                acc2[1][nt] = __builtin_amdgcn_mfma_f32_16x16x32_bf16(wf, ab[1][ks], acc2[1][nt], 0, 0, 0);
            }
        #pragma unroll
        for (int nt = 0; nt < 7; ++nt)
            if (nt * 16 + q * 4 < L1N)
                #pragma unroll
                for (int u = 0; u < 2; ++u) {
                    bf16x4 pk;
                    #pragma unroll
                    for (int i = 0; i < 4; ++i) pk[i] = (short)f2bf(fmaxf(acc2[u][nt][i], 0.f));
                    *(bf16x4*)&X[(u * 16 + c) * K_STRIDE + nt * 16 + q * 4] = pk;
                }

        // ---- GEMM3: heads = [Wm;Wc] @ x2^T ----
        bf16x8 ab3[2][4];
        #pragma unroll
        for (int u = 0; u < 2; ++u)
            #pragma unroll
            for (int ks = 0; ks < 4; ++ks)
                ab3[u][ks] = *(const bf16x8*)&X[(u * 16 + c) * K_STRIDE + ks * 32 + q * 8];
        f32x4 acc3[2][2];
        #pragma unroll
        for (int u = 0; u < 2; ++u) { acc3[u][0] = bias3[0]; acc3[u][1] = bias3[1]; }
        #pragma unroll
        for (int ks = 0; ks < 4; ++ks)
            #pragma unroll
            for (int ht = 0; ht < 2; ++ht) {
                int wr = ht * 16 + c; wr = wr < 27 ? wr : 26;
                bf16x8 wf = *(const bf16x8*)&Whs[wr * K_STRIDE + ks * 32 + q * 8];
                acc3[0][ht] = __builtin_amdgcn_mfma_f32_16x16x32_bf16(wf, ab3[0][ks], acc3[0][ht], 0, 0, 0);
                acc3[1][ht] = __builtin_amdgcn_mfma_f32_16x16x32_bf16(wf, ab3[1][ks], acc3[1][ht], 0, 0, 0);
            }

        // ---- epilogue: lane owns 8 features of row rowW+u*16+c ----
        #pragma unroll
        for (int u = 0; u < 2; ++u) {
            const long r = rowW + u * 16 + c;
            float* mrow = out_mean + r * 6;
            float* crow = out_chol + r * 36;
            #pragma unroll
            for (int ht = 0; ht < 2; ++ht)
                #pragma unroll
                for (int i = 0; i < 4; ++i) {
                    int e = ht * 4 + i;
                    float v = acc3[u][ht][i];
                    if (ekind[e] == 0)      mrow[eoff[e]] = fast_tanh(v);
                    else if (ekind[e] == 1) crow[eoff[e]] = fast_softplus(v);
                }
        }
        #pragma unroll
        for (int it = 0; it < 8; ++it) {       // 480 upper-tri zeros / 64 lanes
            int idx = it * 64 + lane;
            if (idx < 480)
                out_chol[(rowW + zrow_[it]) * 36 + zoff_[it]] = 0.f;
        }
    }
}

extern "C" void kernel_launch(void* const* d_in, const int* in_sizes, int n_in,
                              void* d_out, int out_size, void* d_ws, size_t ws_size,
                              hipStream_t stream) {
    const float* states = (const float*)d_in[0];
    const float* W1 = (const float*)d_in[1];
    const float* b1 = (const float*)d_in[2];
    const float* W2 = (const float*)d_in[3];
    const float* b2 = (const float*)d_in[4];
    const float* Wm = (const float*)d_in[5];
    const float* bm = (const float*)d_in[6];
    const float* Wc = (const float*)d_in[7];
    const float* bc = (const float*)d_in[8];

    const int batch = in_sizes[0] / STATE;                  // 262144
    float* out_mean = (float*)d_out;                        // [B,6]
    float* out_chol = out_mean + (size_t)batch * 6;         // [B,6,6]
    unsigned* img = (unsigned*)d_ws;

    hipFuncSetAttribute((const void*)actor_mfma,
                        hipFuncAttributeMaxDynamicSharedMemorySize, LDS_BYTES);

    prep_weights<<<(IMG_U32 + 255) / 256, 256, 0, stream>>>(W1, W2, Wm, Wc, img);
    const int ntiles = batch / 128;                         // 2048
    actor_mfma<<<GRID, 256, LDS_BYTES, stream>>>(states, img, b1, b2, bm, bc,
                                                 out_mean, out_chol, ntiles);
}

// Round 5
// 113.249 us; speedup vs baseline: 1.0946x; 1.0946x over previous
//
#include <hip/hip_runtime.h>
#include <hip/hip_bf16.h>
#include <math.h>

typedef short bf16x8 __attribute__((ext_vector_type(8)));
typedef short bf16x4 __attribute__((ext_vector_type(4)));
typedef float f32x4 __attribute__((ext_vector_type(4)));

#define STATE 24
#define L1N 100

// ---- bf16 weight image in d_ws (u32 units), biases folded in ----
// W1: 100 rows x 20 u32 (40 halves), col24 = b1, col25..39 = 0
// W2: 100 rows x 68 u32 (136 halves), col100 = b2, col101..135 = 0
// Wh: 27 rows x 68 u32, col100 = bias(m/c), col101..135 = 0
#define IMG_W2_U32 2000
#define IMG_U32 10752
#define W1_STRIDE 40
#define K_STRIDE 136

// ---- LDS: W2 + Wh images + 4 per-wave X buffers ----
#define W2_HALVES 13600           // 100*136
#define WH_HALVES 3672            // 27*136
#define X_OFF (W2_HALVES + WH_HALVES)      // 17272
#define X_HALVES (16 * K_STRIDE)           // 2176
#define LDS_HALVES (X_OFF + 4 * X_HALVES)  // 25976
#define LDS_BYTES (LDS_HALVES * 2)         // 51952 B -> 3 blocks/CU
#define GRID 768                  // 3 persistent blocks per CU

__device__ __constant__ int CHOFF[21] = {0,6,7,12,13,14,18,19,20,21,24,25,26,27,28,30,31,32,33,34,35};
__device__ __constant__ int ZOFF[15]  = {1,2,3,4,5,8,9,10,11,15,16,17,22,23,29};

__device__ inline unsigned short f2bf(float f) {
    union { float f; unsigned u; } v; v.f = f;
    unsigned r = v.u + 0x7FFFu + ((v.u >> 16) & 1u);   // RNE
    return (unsigned short)(r >> 16);
}
__device__ inline unsigned pkbf(float lo, float hi) {
    __hip_bfloat162 h = __float22bfloat162_rn(float2{lo, hi});
    return *(const unsigned*)&h;
}
__device__ inline float fast_tanh(float x) {
    float e = __builtin_amdgcn_exp2f(x * 2.8853900817779268f);   // e^{2x}
    return 1.0f - 2.0f * __builtin_amdgcn_rcpf(e + 1.0f);
}
__device__ inline float fast_softplus(float v) {
    float u = __builtin_amdgcn_exp2f(fabsf(v) * -1.4426950408889634f);
    float l = __builtin_amdgcn_logf(1.0f + u) * 0.6931471805599453f;
    return fmaxf(v, 0.0f) + l;
}

// ---- prologue: padded bf16 weight image with biases folded at k=24/k=100 ----
__global__ __launch_bounds__(256) void prep_weights(
    const float* __restrict__ W1, const float* __restrict__ b1,
    const float* __restrict__ W2, const float* __restrict__ b2,
    const float* __restrict__ Wm, const float* __restrict__ bm,
    const float* __restrict__ Wc, const float* __restrict__ bc,
    unsigned* __restrict__ img)
{
    int i = blockIdx.x * 256 + threadIdx.x;
    if (i >= IMG_U32) return;
    float lo = 0.f, hi = 0.f;
    if (i < 2000) {                              // W1 region
        int r = i / 20, k = (i % 20) * 2;
        if (k < STATE)      { lo = W1[r * STATE + k]; hi = W1[r * STATE + k + 1]; }
        else if (k == STATE)  lo = b1[r];        // bias column
    } else if (i < 8800) {                       // W2 region
        int j = i - 2000, r = j / 68, k = (j % 68) * 2;
        if (k < L1N)      { lo = W2[r * L1N + k]; hi = (k + 1 < L1N) ? W2[r * L1N + k + 1] : 0.f; }
        else if (k == L1N)  lo = b2[r];
    } else if (i < 10636) {                      // heads region
        int j = i - 8800, r = j / 68, k = (j % 68) * 2;
        const float* src; float bias;
        if (r < 6) { src = Wm + r * L1N; bias = bm[r]; }
        else       { src = Wc + (r - 6) * L1N; bias = bc[r - 6]; }
        if (k < L1N)      { lo = src[k]; hi = (k + 1 < L1N) ? src[k + 1] : 0.f; }
        else if (k == L1N)  lo = bias;
    }
    img[i] = pkbf(lo, hi);
}

// A = weights (M = features), B = activations (N = batch rows).
// D lane map: col=lane&15 = batch row, row=q*4+i = feature.
__global__ __launch_bounds__(256, 3) void actor_mfma(
    const float* __restrict__ states,
    const unsigned* __restrict__ img,
    float* __restrict__ out_mean, float* __restrict__ out_chol, int ntiles)
{
    extern __shared__ __align__(16) unsigned short smem[];
    const int tid = threadIdx.x;
    {   // stage W2+Wh image halves into LDS (coalesced b128)
        const uint4* src = (const uint4*)(img + IMG_W2_U32);
        uint4* dst = (uint4*)smem;
        for (int i = tid; i < (IMG_U32 - IMG_W2_U32) / 4; i += 256) dst[i] = src[i];
    }
    const int wave = tid >> 6, lane = tid & 63, q = lane >> 4, c = lane & 15;
    unsigned short* W2s = smem;
    unsigned short* Whs = smem + W2_HALVES;
    unsigned short* X   = smem + X_OFF + wave * X_HALVES;
    unsigned* Xw  = (unsigned*)X;
    float* stage  = (float*)X;    // f32 staging aliased on X, stride 68 dwords,
                                  // cols 0..43 only -> X cols 100..135 survive

    // W1 fragments once from global image (L2/L3-hot, 43 KB shared by all)
    bf16x8 wf1[7];
    #pragma unroll
    for (int nt = 0; nt < 7; ++nt) {
        int wr = nt * 16 + c; wr = wr < L1N ? wr : L1N - 1;
        wf1[nt] = *(const bf16x8*)((const unsigned short*)img + wr * W1_STRIDE + q * 8);
    }

    __syncthreads();   // image staged (staging overruns into X w0; re-init next)

    // init own-wave X pad cols 100..135: col100 = bf16(1.0) (bias lane), rest 0
    #pragma unroll
    for (int it = 0; it < 5; ++it) {
        int idx = it * 64 + lane;
        if (idx < 288) {
            int r = idx / 18, s = idx - r * 18;
            Xw[r * 68 + 50 + s] = (s == 0) ? 0x00003F80u : 0u;
        }
    }

    // per-lane epilogue routing (stage dword col per acc element)
    int scol[8], skind[8];
    #pragma unroll
    for (int ht = 0; ht < 2; ++ht)
        #pragma unroll
        for (int i = 0; i < 4; ++i) {
            int f = ht * 16 + q * 4 + i, e = ht * 4 + i;
            if (f < 6)       { scol[e] = 36 + f;        skind[e] = 0; }
            else if (f < 27) { scol[e] = CHOFF[f - 6];  skind[e] = 1; }
            else             { scol[e] = 0;             skind[e] = -1; }
        }
    int zcol[4];
    const int nz = (q == 3) ? 3 : 4;
    #pragma unroll
    for (int z = 0; z < 4; ++z) zcol[z] = ZOFF[(q * 4 + z) < 15 ? (q * 4 + z) : 14];

    float4 sv[2];
    auto loadStates = [&](int tt) {
        if (tt < ntiles && q < 3) {
            const float* p = states + ((long)tt * 64 + wave * 16 + c) * STATE + q * 8;
            sv[0] = *(const float4*)p;
            sv[1] = *(const float4*)(p + 4);
        }
    };
    loadStates(blockIdx.x);

    for (int t = blockIdx.x; t < ntiles; t += GRID) {
        const long rowW = (long)t * 64 + wave * 16;

        union { bf16x8 v; unsigned u[4]; } sb;
        if (q < 3) {
            sb.u[0] = pkbf(sv[0].x, sv[0].y); sb.u[1] = pkbf(sv[0].z, sv[0].w);
            sb.u[2] = pkbf(sv[1].x, sv[1].y); sb.u[3] = pkbf(sv[1].z, sv[1].w);
        } else {                      // k=24 carries constant 1.0 -> bias term
            sb.u[0] = 0x00003F80u; sb.u[1] = sb.u[2] = sb.u[3] = 0u;
        }
        loadStates(t + GRID);

        // ---- GEMM1: x1 = relu(W1 @ s^T) (bias via k=24) ----
        #pragma unroll
        for (int nt = 0; nt < 7; ++nt) {
            f32x4 acc = {0.f, 0.f, 0.f, 0.f};
            acc = __builtin_amdgcn_mfma_f32_16x16x32_bf16(wf1[nt], sb.v, acc, 0, 0, 0);
            if (nt * 16 + q * 4 < L1N) {
                bf16x4 pk;
                #pragma unroll
                for (int i = 0; i < 4; ++i) pk[i] = (short)f2bf(fmaxf(acc[i], 0.f));
                *(bf16x4*)&X[c * K_STRIDE + nt * 16 + q * 4] = pk;
            }
        }

        // ---- GEMM2: x2 = relu(W2 @ x1^T), K=128 (col100 = 1.0 -> bias) ----
        bf16x8 ab[4];
        #pragma unroll
        for (int ks = 0; ks < 4; ++ks)
            ab[ks] = *(const bf16x8*)&X[c * K_STRIDE + ks * 32 + q * 8];
        f32x4 acc2[7];
        #pragma unroll
        for (int nt = 0; nt < 7; ++nt) acc2[nt] = (f32x4){0.f, 0.f, 0.f, 0.f};
        #pragma unroll
        for (int ks = 0; ks < 4; ++ks)
            #pragma unroll
            for (int nt = 0; nt < 7; ++nt) {
                int wr = nt * 16 + c; wr = wr < L1N ? wr : L1N - 1;
                bf16x8 wf = *(const bf16x8*)&W2s[wr * K_STRIDE + ks * 32 + q * 8];
                acc2[nt] = __builtin_amdgcn_mfma_f32_16x16x32_bf16(wf, ab[ks], acc2[nt], 0, 0, 0);
            }
        #pragma unroll
        for (int nt = 0; nt < 7; ++nt)
            if (nt * 16 + q * 4 < L1N) {
                bf16x4 pk;
                #pragma unroll
                for (int i = 0; i < 4; ++i) pk[i] = (short)f2bf(fmaxf(acc2[nt][i], 0.f));
                *(bf16x4*)&X[c * K_STRIDE + nt * 16 + q * 4] = pk;
            }

        // ---- GEMM3: heads = [Wm;Wc] @ x2^T (bias via col100) ----
        bf16x8 ab3[4];
        #pragma unroll
        for (int ks = 0; ks < 4; ++ks)
            ab3[ks] = *(const bf16x8*)&X[c * K_STRIDE + ks * 32 + q * 8];
        f32x4 acc3[2];
        acc3[0] = (f32x4){0.f, 0.f, 0.f, 0.f};
        acc3[1] = (f32x4){0.f, 0.f, 0.f, 0.f};
        #pragma unroll
        for (int ks = 0; ks < 4; ++ks)
            #pragma unroll
            for (int ht = 0; ht < 2; ++ht) {
                int wr = ht * 16 + c; wr = wr < 27 ? wr : 26;
                bf16x8 wf = *(const bf16x8*)&Whs[wr * K_STRIDE + ks * 32 + q * 8];
                acc3[ht] = __builtin_amdgcn_mfma_f32_16x16x32_bf16(wf, ab3[ks], acc3[ht], 0, 0, 0);
            }

        // ---- stage epilogue into LDS (row c, cols 0..35 chol / 36..41 mean) ----
        #pragma unroll
        for (int e = 0; e < 8; ++e) {
            float v = acc3[e >> 2][e & 3];
            if (skind[e] == 0)      stage[c * 68 + scol[e]] = fast_tanh(v);
            else if (skind[e] == 1) stage[c * 68 + scol[e]] = fast_softplus(v);
        }
        #pragma unroll
        for (int z = 0; z < 4; ++z)
            if (z < nz) stage[c * 68 + zcol[z]] = 0.f;

        // ---- coalesced global stores (same-wave DS ordering covers RAW) ----
        if (lane < 48) {   // mean: 16 rows x 6 f32 = 48 float2, contiguous
            float2 m = *(const float2*)&stage[(lane / 3) * 68 + 36 + (lane % 3) * 2];
            *(float2*)(out_mean + rowW * 6 + lane * 2) = m;
        }
        #pragma unroll
        for (int it = 0; it < 3; ++it) {   // chol: 16 x 36 f32 = 144 float4
            int j = it * 64 + lane;
            if (j < 144) {
                float4 v = *(const float4*)&stage[(j / 9) * 68 + (j % 9) * 4];
                *(float4*)(out_chol + rowW * 36 + j * 4) = v;
            }
        }
    }
}

extern "C" void kernel_launch(void* const* d_in, const int* in_sizes, int n_in,
                              void* d_out, int out_size, void* d_ws, size_t ws_size,
                              hipStream_t stream) {
    const float* states = (const float*)d_in[0];
    const float* W1 = (const float*)d_in[1];
    const float* b1 = (const float*)d_in[2];
    const float* W2 = (const float*)d_in[3];
    const float* b2 = (const float*)d_in[4];
    const float* Wm = (const float*)d_in[5];
    const float* bm = (const float*)d_in[6];
    const float* Wc = (const float*)d_in[7];
    const float* bc = (const float*)d_in[8];

    const int batch = in_sizes[0] / STATE;                  // 262144
    float* out_mean = (float*)d_out;                        // [B,6]
    float* out_chol = out_mean + (size_t)batch * 6;         // [B,6,6]
    unsigned* img = (unsigned*)d_ws;

    hipFuncSetAttribute((const void*)actor_mfma,
                        hipFuncAttributeMaxDynamicSharedMemorySize, LDS_BYTES);

    prep_weights<<<(IMG_U32 + 255) / 256, 256, 0, stream>>>(W1, b1, W2, b2,
                                                            Wm, bm, Wc, bc, img);
    const int ntiles = batch / 64;                          // 4096 (64 rows/tile)
    actor_mfma<<<GRID, 256, LDS_BYTES, stream>>>(states, img, out_mean, out_chol, ntiles);
}